// Round 1
// baseline (883.414 us; speedup 1.0000x reference)
//
#include <hip/hip_runtime.h>
#include <hip/hip_bf16.h>

// WeightedTopDownTreeLSTMEndtoEnd on MI355X.
// Tree: parent(i) = (i-1)/10, levels are contiguous: [0,1,11,111,1111).
// Per level: fused GEMM [rows x 576] * [576 x 1024] (+gating), bf16 MFMA.

#define NNODES 1111
#define BATCH  128
#define MDIM   256
#define DIN    300
#define NBM    (NNODES * BATCH * MDIM)      // 36,405,248 floats per c/h section
#define KPADX  320                          // Din padded to multiple of 32
#define NCHUNK 18                           // 576 / 32
#define CHUNK_ELEMS (256 * 32)              // W-chunk bf16 elems = 8192
#define PACKW_ELEMS (4 * NCHUNK * CHUNK_ELEMS)  // 589,824

typedef __attribute__((ext_vector_type(8))) short s16x8;   // 8 bf16 (4 VGPRs)
typedef __attribute__((ext_vector_type(4))) float f32x4;   // MFMA accumulator

__device__ __forceinline__ ushort f2bf(float f) {
    union { float f; unsigned u; } v; v.f = f;
    unsigned u = v.u;
    return (ushort)((u + 0x7FFFu + ((u >> 16) & 1u)) >> 16);  // RNE
}

__device__ __forceinline__ float sigmoidf_(float x) {
    return 1.0f / (1.0f + __expf(-x));
}

// ---------------------------------------------------------------------------
// Prep: pack weights to bf16 [strip s][chunk ck][lrow 0..255][k 0..31].
// lrow -> gate g = lrow>>6, rowin = lrow&63 -> W' row j = g*256 + s*64 + rowin.
// k global = ck*32 + kl:  k<300 -> Wioux/Wfx ; 300..319 -> 0 ; >=320 -> Wiouh/Wfh.
// Also fused bias[1024]: iou gates get bioux+biouh, f gate gets bfx+bfh.
// ---------------------------------------------------------------------------
__global__ void prep_kernel(
    const float* __restrict__ Wioux, const float* __restrict__ bioux,
    const float* __restrict__ Wiouh, const float* __restrict__ biouh,
    const float* __restrict__ Wfx,   const float* __restrict__ bfx,
    const float* __restrict__ Wfh,   const float* __restrict__ bfh,
    ushort* __restrict__ packW, float* __restrict__ bias)
{
    const int idx = blockIdx.x * 256 + threadIdx.x;
    if (idx < PACKW_ELEMS) {
        const int s    = idx / (NCHUNK * CHUNK_ELEMS);
        const int rem  = idx % (NCHUNK * CHUNK_ELEMS);
        const int ck   = rem / CHUNK_ELEMS;
        const int e    = rem % CHUNK_ELEMS;
        const int lrow = e >> 5;
        const int kl   = e & 31;
        const int g    = lrow >> 6;
        const int rowin = lrow & 63;
        const int j    = g * 256 + s * 64 + rowin;      // 0..1023
        const int k    = ck * 32 + kl;                  // 0..575
        float val;
        if (k < DIN) {
            val = (j < 768) ? Wioux[j * DIN + k] : Wfx[(j - 768) * DIN + k];
        } else if (k < KPADX) {
            val = 0.0f;
        } else {
            const int kr = k - KPADX;
            val = (j < 768) ? Wiouh[j * MDIM + kr] : Wfh[(j - 768) * MDIM + kr];
        }
        packW[idx] = f2bf(val);
    }
    if (idx < 1024) {
        bias[idx] = (idx < 768) ? (bioux[idx] + biouh[idx])
                                : (bfx[idx - 768] + bfh[idx - 768]);
    }
}

// ---------------------------------------------------------------------------
// Per-level fused kernel. Block = one node's 128 batch rows x 64 m-cols
// (= 256 gate-cols scattered as 4 strips of 64 W'-rows).
// 512 threads = 8 waves: wave (wr = w>>2 in {0,1} row-half, wm = w&3 m-substrip).
// Per wave: 4 row-tiles x 4 gates of mfma_f32_16x16x32_bf16, K-loop of 32-chunks.
// LDS: A chunk [128][32] bf16 (8KB) + W chunk [256][32] bf16 (16KB), both
// XOR-swizzled (byte ^= (row&7)<<4) to kill the 64B-row-stride bank conflict.
// ---------------------------------------------------------------------------
__global__ __launch_bounds__(512) void tree_level_kernel(
    const float* __restrict__ inputs, const float* __restrict__ prob,
    const ushort* __restrict__ packW, const float* __restrict__ bias,
    float* __restrict__ out, int level_start, int hasParent)
{
    __shared__ __align__(16) ushort ldsA[BATCH * 32];   // 8 KB
    __shared__ __align__(16) ushort ldsW[256 * 32];     // 16 KB
    char* pA = (char*)ldsA;
    char* pW = (char*)ldsW;

    const int tid   = threadIdx.x;
    const int node  = level_start + blockIdx.x;
    const int strip = blockIdx.y;            // 0..3  -> m-cols [strip*64, +64)
    const int c0    = strip * 64;

    int parent = 0;
    float scale = 0.0f;
    if (hasParent) {
        parent = (node - 1) / 10;
        scale  = prob[(size_t)parent * NNODES + node];
    }
    const float* cprev = out + ((size_t)parent * BATCH) * MDIM;          // c section
    const float* hprev = out + NBM + ((size_t)parent * BATCH) * MDIM;    // h section

    const int wave = tid >> 6;
    const int lane = tid & 63;
    const int wr   = wave >> 2;          // row half (0..1)
    const int wm   = wave & 3;           // m substrip (0..3)
    const int l15  = lane & 15;
    const int kqb  = (lane >> 4) * 16;   // k-quarter byte offset (8 bf16 = 16B)

    f32x4 acc[4][4];
    const f32x4 zero4 = {0.f, 0.f, 0.f, 0.f};
#pragma unroll
    for (int t = 0; t < 4; ++t)
#pragma unroll
        for (int g = 0; g < 4; ++g) acc[t][g] = zero4;

    // staging assignment: thread -> (row, 16B segment)
    const int srow = tid >> 2;           // 0..127
    const int skl  = (tid & 3) * 8;      // k element offset 0/8/16/24
    const float* insrc = inputs + ((size_t)node * BATCH + srow) * DIN;
    const float* hsrc  = hprev + (size_t)srow * MDIM;
    const int aOff = (srow * 64 + skl * 2) ^ ((srow & 7) << 4);

    const int kchunks = hasParent ? NCHUNK : 10;   // root: no recurrent part

    for (int ck = 0; ck < kchunks; ++ck) {
        // ---- stage A chunk [128][32] (fp32 -> bf16, swizzled) ----
        float v[8];
        if (ck < 10) {
            const int gk = ck * 32 + skl;
#pragma unroll
            for (int j = 0; j < 8; ++j)
                v[j] = (gk + j < DIN) ? insrc[gk + j] : 0.0f;
        } else {
            const int gk = (ck - 10) * 32 + skl;
#pragma unroll
            for (int j = 0; j < 8; ++j)
                v[j] = scale * hsrc[gk + j];
        }
        union { ushort us[8]; int4 v4; } pk;
#pragma unroll
        for (int j = 0; j < 8; ++j) pk.us[j] = f2bf(v[j]);
        *(int4*)(pA + aOff) = pk.v4;

        // ---- stage W chunk [256][32] from packed (already strip-ordered) ----
        {
            const size_t base = ((size_t)(strip * NCHUNK + ck)) * CHUNK_ELEMS;
#pragma unroll
            for (int h = 0; h < 2; ++h) {
                const int u = tid + h * 512;            // 16B unit 0..1023
                const int lrow = u >> 2, sg = u & 3;
                const int4 w = *(const int4*)(packW + base + (size_t)u * 8);
                *(int4*)(pW + ((lrow * 64 + sg * 16) ^ ((lrow & 7) << 4))) = w;
            }
        }
        __syncthreads();

        // ---- fragments + MFMA ----
        s16x8 af[4], bf[4];
#pragma unroll
        for (int t = 0; t < 4; ++t) {
            const int r = wr * 64 + t * 16 + l15;
            af[t] = *(const s16x8*)(pA + ((r * 64 + kqb) ^ ((r & 7) << 4)));
        }
#pragma unroll
        for (int g = 0; g < 4; ++g) {
            const int r = g * 64 + wm * 16 + l15;
            bf[g] = *(const s16x8*)(pW + ((r * 64 + kqb) ^ ((r & 7) << 4)));
        }
#pragma unroll
        for (int t = 0; t < 4; ++t)
#pragma unroll
            for (int g = 0; g < 4; ++g)
                acc[t][g] = __builtin_amdgcn_mfma_f32_16x16x32_bf16(
                    af[t], bf[g], acc[t][g], 0, 0, 0);
        __syncthreads();
    }

    // ---- epilogue: gating + write c,h ----
    const int m = c0 + wm * 16 + l15;     // output feature col, fixed per lane
    const float bi = bias[m];
    const float bo = bias[256 + m];
    const float bu = bias[512 + m];
    const float bfv = bias[768 + m];
    float* cOut = out;
    float* hOut = out + NBM;

#pragma unroll
    for (int t = 0; t < 4; ++t) {
        const int b0 = wr * 64 + t * 16 + ((lane >> 4) << 2);
#pragma unroll
        for (int r = 0; r < 4; ++r) {
            const int brow = b0 + r;
            const float iv = acc[t][0][r] + bi;
            const float ov = acc[t][1][r] + bo;
            const float uv = acc[t][2][r] + bu;
            const float fv = acc[t][3][r] + bfv;
            float pc = 0.0f;
            if (hasParent) pc = scale * cprev[(size_t)brow * MDIM + m];
            const float cn = sigmoidf_(iv) * tanhf(uv) + sigmoidf_(fv) * pc;
            const float hn = sigmoidf_(ov) * tanhf(cn);
            const size_t o = ((size_t)node * BATCH + brow) * MDIM + m;
            cOut[o] = cn;
            hOut[o] = hn;
        }
    }
}

// ---------------------------------------------------------------------------
extern "C" void kernel_launch(void* const* d_in, const int* in_sizes, int n_in,
                              void* d_out, int out_size, void* d_ws, size_t ws_size,
                              hipStream_t stream) {
    const float* inputs = (const float*)d_in[0];
    const float* prob   = (const float*)d_in[1];
    const float* Wioux  = (const float*)d_in[2];
    const float* bioux  = (const float*)d_in[3];
    const float* Wiouh  = (const float*)d_in[4];
    const float* biouh  = (const float*)d_in[5];
    const float* Wfx    = (const float*)d_in[6];
    const float* bfx    = (const float*)d_in[7];
    const float* Wfh    = (const float*)d_in[8];
    const float* bfh    = (const float*)d_in[9];
    float* out = (float*)d_out;

    // ws layout: packW bf16 [589824] (1,179,648 B) then bias f32 [1024]
    ushort* packW = (ushort*)d_ws;
    float*  bias  = (float*)((char*)d_ws + (size_t)PACKW_ELEMS * 2);

    prep_kernel<<<(PACKW_ELEMS + 255) / 256, 256, 0, stream>>>(
        Wioux, bioux, Wiouh, biouh, Wfx, bfx, Wfh, bfh, packW, bias);

    // level-synchronous top-down pass (contiguous node ranges per depth)
    tree_level_kernel<<<dim3(1,    4), 512, 0, stream>>>(inputs, prob, packW, bias, out,   0, 0);
    tree_level_kernel<<<dim3(10,   4), 512, 0, stream>>>(inputs, prob, packW, bias, out,   1, 1);
    tree_level_kernel<<<dim3(100,  4), 512, 0, stream>>>(inputs, prob, packW, bias, out,  11, 1);
    tree_level_kernel<<<dim3(1000, 4), 512, 0, stream>>>(inputs, prob, packW, bias, out, 111, 1);
}

// Round 3
// 739.897 us; speedup vs baseline: 1.1940x; 1.1940x over previous
//
#include <hip/hip_runtime.h>
#include <hip/hip_bf16.h>

// WeightedTopDownTreeLSTMEndtoEnd on MI355X (gfx950).
// Levels are contiguous: [0,1), [1,11), [11,111), [111,1111); parent(i)=(i-1)/10.
// Per level:
//   proj  (prev level nodes): HF[p] = h[p] . [Wiouh;Wfh]^T   (bf16, shared by 10 children)
//   child (this level nodes): gates = inputs . [Wioux;Wfx]^T + scale*HF[parent] + bias -> gating
// Both are bf16-MFMA GEMMs with a 2-phase double-buffered LDS pipeline,
// global_load_lds for the (pre-inverse-swizzled) packed weights, XOR-swizzled LDS.

#define NNODES 1111
#define BATCH  128
#define MDIM   256
#define DIN    300
#define NBM    (NNODES * BATCH * MDIM)      // floats per c/h section
#define NCK_X  10                           // child K chunks (K=320, Din padded)
#define NCK_H  8                            // proj K chunks (K=256)
#define CHUNK_ELEMS 8192                    // W chunk: 256 rows x 32 k (bf16)
#define XW_ELEMS (4 * NCK_X * CHUNK_ELEMS)  // 327680
#define HW_ELEMS (4 * NCK_H * CHUNK_ELEMS)  // 262144

typedef __attribute__((ext_vector_type(8))) short s16x8;   // 8 bf16
typedef __attribute__((ext_vector_type(4))) float f32x4;   // MFMA acc

__device__ __forceinline__ ushort f2bf(float f) {
    union { float f; unsigned u; } v; v.f = f;
    unsigned u = v.u;
    return (ushort)((u + 0x7FFFu + ((u >> 16) & 1u)) >> 16);  // RNE
}
__device__ __forceinline__ float bf2f(ushort u) {
    union { unsigned u; float f; } v; v.u = ((unsigned)u) << 16;
    return v.f;
}
__device__ __forceinline__ float sigmoidf_(float x) { return 1.0f / (1.0f + __expf(-x)); }

// forward LDS swizzle on byte address (64B rows, 8-row / 512B groups)
__device__ __forceinline__ int swz(int a) { return a ^ (((a >> 6) & 7) << 4); }

// ---------------------------------------------------------------------------
// Prep: pack weights bf16, PRE-INVERSE-SWIZZLED so that a linear
// global_load_lds write + swz() ds_read yields W'[row][k].
// Layouts: packWx [strip][ck<10][16KB chunk], row j = g*256 + strip*64 + rowin,
//          k = ck*32+kl (k>=300 zero-pad). packWh same with k in [0,256).
// Fused bias[1024]: iou -> bioux+biouh, f -> bfx+bfh.
// ---------------------------------------------------------------------------
__global__ void prep_kernel(
    const float* __restrict__ Wioux, const float* __restrict__ bioux,
    const float* __restrict__ Wiouh, const float* __restrict__ biouh,
    const float* __restrict__ Wfx,   const float* __restrict__ bfx,
    const float* __restrict__ Wfh,   const float* __restrict__ bfh,
    ushort* __restrict__ packWx, ushort* __restrict__ packWh,
    float* __restrict__ bias)
{
    const int idx = blockIdx.x * 256 + threadIdx.x;
    if (idx < XW_ELEMS + HW_ELEMS) {
        const bool isX = idx < XW_ELEMS;
        const int id   = isX ? idx : idx - XW_ELEMS;
        const int nck  = isX ? NCK_X : NCK_H;
        const int strip = id / (nck * CHUNK_ELEMS);
        const int rem   = id % (nck * CHUNK_ELEMS);
        const int ck    = rem / CHUNK_ELEMS;
        const int e     = rem % CHUNK_ELEMS;
        // inverse of swz() on byte position pb within the 16KB chunk
        const int pb  = e * 2;
        const int grp = pb >> 9;
        const int low = pb & 511;
        const int b4 = (low >> 4) & 1, b5 = (low >> 5) & 1, b6 = (low >> 6) & 1;
        const int b7 = (low >> 7) & 1, b8 = (low >> 8) & 1;
        const int a6 = b6 ^ b8, a5 = b5 ^ b7, a4 = b4 ^ a6;
        const int a = (grp << 9) | (low & 15) | (a4 << 4) | (a5 << 5) | (a6 << 6) | (b7 << 7) | (b8 << 8);
        const int lrow = a >> 6;            // 0..255
        const int kl   = (a & 63) >> 1;     // 0..31
        const int g = lrow >> 6, rowin = lrow & 63;
        const int j = g * 256 + strip * 64 + rowin;   // 0..1023
        const int k = ck * 32 + kl;
        float val = 0.0f;
        if (isX) {
            if (k < DIN) val = (j < 768) ? Wioux[j * DIN + k] : Wfx[(j - 768) * DIN + k];
            packWx[id] = f2bf(val);
        } else {
            val = (j < 768) ? Wiouh[j * MDIM + k] : Wfh[(j - 768) * MDIM + k];
            packWh[id] = f2bf(val);
        }
    } else if (idx < XW_ELEMS + HW_ELEMS + 1024) {
        const int b = idx - XW_ELEMS - HW_ELEMS;
        bias[b] = (b < 768) ? (bioux[b] + biouh[b]) : (bfx[b - 768] + bfh[b - 768]);
    }
}

// ---------------------------------------------------------------------------
// Level kernel. Block = (node, strip): 128 batch rows x 64 m-cols (x4 gates).
// MODE 0: child, no parent (root). MODE 1: child. MODE 2: proj (HF = h.Wh^T).
// 512 threads / 8 waves (wr=wave>>2 row-half, wm=wave&3 m-substrip).
// 2-phase pipeline: one s_barrier per K-chunk; A reg-staged (fp32->bf16),
// W via global_load_lds from pre-swizzled packW; double-buffered LDS.
// ---------------------------------------------------------------------------
template<int MODE>
__global__ __launch_bounds__(512, 4) void level_kernel(
    const float* __restrict__ Asrc,   // inputs (child) or h section (proj)
    const float* __restrict__ prob,
    const ushort* __restrict__ packW, // packWx (child) or packWh (proj)
    const float* __restrict__ bias,
    float* __restrict__ out,          // [c | h] sections
    ushort* __restrict__ HF,          // proj: write; child MODE1: read
    int level_start, int plevel_start)
{
    constexpr int NCK = (MODE == 2) ? NCK_H : NCK_X;
    constexpr int AST = (MODE == 2) ? MDIM : DIN;   // A row stride (floats)

    __shared__ __align__(16) ushort ldsA[2][BATCH * 32];   // 2 x 8 KB
    __shared__ __align__(16) ushort ldsW[2][256 * 32];     // 2 x 16 KB

    const int tid   = threadIdx.x;
    const int node  = level_start + (blockIdx.x >> 2);
    const int strip = blockIdx.x & 3;
    const int c0    = strip * 64;

    int parent = 0; float scale = 0.0f;
    if (MODE == 1) {
        parent = (node - 1) / 10;
        scale  = prob[(size_t)parent * NNODES + node];
    }

    const int wave = tid >> 6, lane = tid & 63;
    const int wr = wave >> 2, wm = wave & 3;
    const int l15 = lane & 15, kq = lane >> 4;

    f32x4 acc[4][4];
    const f32x4 zero4 = {0.f, 0.f, 0.f, 0.f};
#pragma unroll
    for (int t = 0; t < 4; ++t)
#pragma unroll
        for (int g = 0; g < 4; ++g) acc[t][g] = zero4;

    // A staging: thread -> (row srow, 16B segment)
    const int srow = tid >> 2;
    const int se8  = (tid & 3) * 8;                 // element offset 0/8/16/24
    const float* arow = Asrc + ((size_t)node * BATCH + srow) * AST;
    const int aOff = swz(srow * 64 + se8 * 2);      // same for both buffers

    // fragment LDS offsets (constant across chunks)
    int aoff[4], boff[4];
#pragma unroll
    for (int t = 0; t < 4; ++t) aoff[t] = swz((wr * 64 + t * 16 + l15) * 64 + kq * 16);
#pragma unroll
    for (int g = 0; g < 4; ++g) boff[g] = swz((g * 64 + wm * 16 + l15) * 64 + kq * 16);

    const ushort* wbase = packW + (size_t)(strip * NCK) * CHUNK_ELEMS;

    float4 va0, va1;
    auto issueA = [&](int ck) {
        const float* p = arow + ck * 32 + se8;
        va0 = *(const float4*)p;         // rows are 16B-aligned; slight tail
        va1 = *(const float4*)(p + 4);   // overread past k=300 is masked below
    };
    auto writeA = [&](int ck, int buf) {
        float v[8] = {va0.x, va0.y, va0.z, va0.w, va1.x, va1.y, va1.z, va1.w};
        if (MODE != 2) {
            const int ge = ck * 32 + se8;
            if (ge + 7 >= DIN) {
#pragma unroll
                for (int j = 0; j < 8; ++j) if (ge + j >= DIN) v[j] = 0.0f;
            }
        }
        union { ushort us[8]; int4 q; } pk;
#pragma unroll
        for (int j = 0; j < 8; ++j) pk.us[j] = f2bf(v[j]);
        *(int4*)((char*)ldsA[buf] + aOff) = pk.q;
    };
    auto issueW = [&](int ck, int buf) {
        const ushort* g0 = wbase + (size_t)ck * CHUNK_ELEMS + wave * 1024 + lane * 8;
        ushort* l0 = &ldsW[buf][wave * 1024];
        __builtin_amdgcn_global_load_lds(
            (const __attribute__((address_space(1))) unsigned*)(const void*)g0,
            (__attribute__((address_space(3))) unsigned*)(void*)l0, 16, 0, 0);
        __builtin_amdgcn_global_load_lds(
            (const __attribute__((address_space(1))) unsigned*)(const void*)(g0 + 512),
            (__attribute__((address_space(3))) unsigned*)(void*)(l0 + 512), 16, 0, 0);
    };

    // prologue: stage chunk 0 into buf 0
    issueA(0);
    issueW(0, 0);
    writeA(0, 0);
    asm volatile("s_waitcnt vmcnt(0) lgkmcnt(0)" ::: "memory");
    __builtin_amdgcn_sched_barrier(0);
    __builtin_amdgcn_s_barrier();
    __builtin_amdgcn_sched_barrier(0);

    int cur = 0;
    for (int t = 0; t < NCK - 1; ++t) {
        issueA(t + 1);                 // global loads in flight across MFMA phase
        issueW(t + 1, cur ^ 1);
        s16x8 af[4], bfr[4];
        char* pA = (char*)ldsA[cur];
        char* pW = (char*)ldsW[cur];
#pragma unroll
        for (int i = 0; i < 4; ++i) af[i] = *(const s16x8*)(pA + aoff[i]);
#pragma unroll
        for (int g = 0; g < 4; ++g) bfr[g] = *(const s16x8*)(pW + boff[g]);
#pragma unroll
        for (int i = 0; i < 4; ++i)
#pragma unroll
            for (int g = 0; g < 4; ++g)
                acc[i][g] = __builtin_amdgcn_mfma_f32_16x16x32_bf16(af[i], bfr[g], acc[i][g], 0, 0, 0);
        writeA(t + 1, cur ^ 1);
        asm volatile("s_waitcnt vmcnt(0) lgkmcnt(0)" ::: "memory");
        __builtin_amdgcn_sched_barrier(0);
        __builtin_amdgcn_s_barrier();
        __builtin_amdgcn_sched_barrier(0);
        cur ^= 1;
    }
    {   // last chunk (already staged)
        s16x8 af[4], bfr[4];
        char* pA = (char*)ldsA[cur];
        char* pW = (char*)ldsW[cur];
#pragma unroll
        for (int i = 0; i < 4; ++i) af[i] = *(const s16x8*)(pA + aoff[i]);
#pragma unroll
        for (int g = 0; g < 4; ++g) bfr[g] = *(const s16x8*)(pW + boff[g]);
#pragma unroll
        for (int i = 0; i < 4; ++i)
#pragma unroll
            for (int g = 0; g < 4; ++g)
                acc[i][g] = __builtin_amdgcn_mfma_f32_16x16x32_bf16(af[i], bfr[g], acc[i][g], 0, 0, 0);
    }

    // ---- epilogue ----
    const int m = c0 + wm * 16 + l15;   // feature col 0..255, fixed per lane

    if (MODE == 2) {
        // write HF[node - level_start][brow][g*256 + m] as bf16
        ushort* hfw = HF + (size_t)(node - level_start) * BATCH * 1024;
#pragma unroll
        for (int t = 0; t < 4; ++t) {
            const int b0 = wr * 64 + t * 16 + (kq << 2);
#pragma unroll
            for (int r = 0; r < 4; ++r) {
                const int brow = b0 + r;
#pragma unroll
                for (int g = 0; g < 4; ++g)
                    hfw[(size_t)brow * 1024 + g * 256 + m] = f2bf(acc[t][g][r]);
            }
        }
        return;
    }

    const float bi  = bias[m];
    const float bo  = bias[256 + m];
    const float bu  = bias[512 + m];
    const float bfv = bias[768 + m];
    const float* cprev = out + (size_t)parent * BATCH * MDIM;
    const ushort* hfb = (MODE == 1) ? (HF + (size_t)(parent - plevel_start) * BATCH * 1024) : (const ushort*)0;
    float* cOut = out;
    float* hOut = out + NBM;

#pragma unroll
    for (int t = 0; t < 4; ++t) {
        const int b0 = wr * 64 + t * 16 + (kq << 2);
#pragma unroll
        for (int r = 0; r < 4; ++r) {
            const int brow = b0 + r;
            float hi = 0.f, ho = 0.f, hu = 0.f, hff = 0.f, pc = 0.f;
            if (MODE == 1) {
                const ushort* hr = hfb + (size_t)brow * 1024;
                hi  = bf2f(hr[m]);
                ho  = bf2f(hr[256 + m]);
                hu  = bf2f(hr[512 + m]);
                hff = bf2f(hr[768 + m]);
                pc  = scale * cprev[(size_t)brow * MDIM + m];
            }
            const float iv = acc[t][0][r] + bi  + scale * hi;
            const float ov = acc[t][1][r] + bo  + scale * ho;
            const float uv = acc[t][2][r] + bu  + scale * hu;
            const float fv = acc[t][3][r] + bfv + scale * hff;
            const float cn = sigmoidf_(iv) * tanhf(uv) + sigmoidf_(fv) * pc;
            const float hn = sigmoidf_(ov) * tanhf(cn);
            const size_t o = ((size_t)node * BATCH + brow) * MDIM + m;
            cOut[o] = cn;
            hOut[o] = hn;
        }
    }
}

// ---------------------------------------------------------------------------
extern "C" void kernel_launch(void* const* d_in, const int* in_sizes, int n_in,
                              void* d_out, int out_size, void* d_ws, size_t ws_size,
                              hipStream_t stream) {
    const float* inputs = (const float*)d_in[0];
    const float* prob   = (const float*)d_in[1];
    const float* Wioux  = (const float*)d_in[2];
    const float* bioux  = (const float*)d_in[3];
    const float* Wiouh  = (const float*)d_in[4];
    const float* biouh  = (const float*)d_in[5];
    const float* Wfx    = (const float*)d_in[6];
    const float* bfx    = (const float*)d_in[7];
    const float* Wfh    = (const float*)d_in[8];
    const float* bfh    = (const float*)d_in[9];
    float* out = (float*)d_out;

    // ws: packWx | packWh | bias | HF  (~27.4 MB total)
    ushort* packWx = (ushort*)d_ws;
    ushort* packWh = packWx + XW_ELEMS;
    float*  bias   = (float*)(packWh + HW_ELEMS);
    ushort* HF     = (ushort*)(bias + 1024);

    const int prepTotal = XW_ELEMS + HW_ELEMS + 1024;
    prep_kernel<<<(prepTotal + 255) / 256, 256, 0, stream>>>(
        Wioux, bioux, Wiouh, biouh, Wfx, bfx, Wfh, bfh, packWx, packWh, bias);

    const float* hsec = out + NBM;

    // level 0 (root)
    level_kernel<0><<<dim3(4),    512, 0, stream>>>(inputs, prob, packWx, bias, out, HF, 0, 0);
    level_kernel<2><<<dim3(4),    512, 0, stream>>>(hsec,   prob, packWh, bias, out, HF, 0, 0);
    // level 1
    level_kernel<1><<<dim3(40),   512, 0, stream>>>(inputs, prob, packWx, bias, out, HF, 1, 0);
    level_kernel<2><<<dim3(40),   512, 0, stream>>>(hsec,   prob, packWh, bias, out, HF, 1, 1);
    // level 2
    level_kernel<1><<<dim3(400),  512, 0, stream>>>(inputs, prob, packWx, bias, out, HF, 11, 1);
    level_kernel<2><<<dim3(400),  512, 0, stream>>>(hsec,   prob, packWh, bias, out, HF, 11, 11);
    // level 3
    level_kernel<1><<<dim3(4000), 512, 0, stream>>>(inputs, prob, packWx, bias, out, HF, 111, 11);
}

// Round 4
// 704.875 us; speedup vs baseline: 1.2533x; 1.0497x over previous
//
#include <hip/hip_runtime.h>
#include <hip/hip_bf16.h>

// WeightedTopDownTreeLSTMEndtoEnd on MI355X (gfx950).
// Levels contiguous: [0,1), [1,11), [11,111), [111,1111); parent(i)=(i-1)/10.
// proj  (parents): HF[p] = h[p] . [Wiouh;Wfh]^T      (bf16 tile-layout, shared by 10 children)
// child (nodes):   gates = inputs~ . [Wioux~;Wfx~]^T (+bias folded at k=319) + scale*HF[parent]
// Both bf16-MFMA GEMMs, 2-phase double-buffered LDS pipeline with COUNTED vmcnt,
// global_load_lds for pre-inverse-swizzled weights, XOR-swizzled LDS reads.

#define NNODES 1111
#define BATCH  128
#define MDIM   256
#define DIN    300
#define NBM    (NNODES * BATCH * MDIM)      // floats per c/h section
#define NCK_X  10                           // child K chunks (K=320; k=319 is bias lane)
#define NCK_H  8                            // proj K chunks (K=256)
#define CHUNK_ELEMS 8192                    // W chunk: 256 rows x 32 k (bf16)
#define XW_ELEMS (4 * NCK_X * CHUNK_ELEMS)  // 327680
#define HW_ELEMS (4 * NCK_H * CHUNK_ELEMS)  // 262144
#define HF_PER_PS 32768                     // elems per (pidx,strip) = 16*512*4
#define HF_PER_P  131072                    // per pidx (4 strips)

typedef __attribute__((ext_vector_type(8))) short s16x8;          // 8 bf16
typedef __attribute__((ext_vector_type(4))) float f32x4;          // MFMA acc
typedef __attribute__((ext_vector_type(4))) unsigned short u16x4; // 8B HF quad

__device__ __forceinline__ ushort f2bf(float f) {                 // RNE (prep only)
    union { float f; unsigned u; } v; v.f = f;
    unsigned u = v.u;
    return (ushort)((u + 0x7FFFu + ((u >> 16) & 1u)) >> 16);
}
__device__ __forceinline__ float bf2f(ushort u) {
    union { unsigned u; float f; } v; v.u = ((unsigned)u) << 16;
    return v.f;
}
__device__ __forceinline__ float sig_(float x) {
    return __builtin_amdgcn_rcpf(1.0f + __expf(-x));
}
__device__ __forceinline__ float tanh_(float x) {
    // 1 - 2/(e^{2x}+1); large |x| saturates correctly via rcp(inf)=0
    return __builtin_fmaf(-2.0f, __builtin_amdgcn_rcpf(__expf(2.0f * x) + 1.0f), 1.0f);
}

// forward LDS swizzle on byte address (64B rows, 8-row / 512B groups)
__device__ __forceinline__ int swz(int a) { return a ^ (((a >> 6) & 7) << 4); }

// ---------------------------------------------------------------------------
// Prep: pack weights bf16, PRE-INVERSE-SWIZZLED so linear global_load_lds +
// swz() ds_read yields W'[row][k]. packWx row j = g*256+strip*64+rowin,
// k=ck*32+kl; k in [300,319) -> 0; k==319 -> fused bias_j. packWh k in [0,256).
// ---------------------------------------------------------------------------
__global__ void prep_kernel(
    const float* __restrict__ Wioux, const float* __restrict__ bioux,
    const float* __restrict__ Wiouh, const float* __restrict__ biouh,
    const float* __restrict__ Wfx,   const float* __restrict__ bfx,
    const float* __restrict__ Wfh,   const float* __restrict__ bfh,
    ushort* __restrict__ packWx, ushort* __restrict__ packWh)
{
    const int idx = blockIdx.x * 256 + threadIdx.x;
    if (idx >= XW_ELEMS + HW_ELEMS) return;
    const bool isX = idx < XW_ELEMS;
    const int id   = isX ? idx : idx - XW_ELEMS;
    const int nck  = isX ? NCK_X : NCK_H;
    const int strip = id / (nck * CHUNK_ELEMS);
    const int rem   = id % (nck * CHUNK_ELEMS);
    const int ck    = rem / CHUNK_ELEMS;
    const int e     = rem % CHUNK_ELEMS;
    // inverse of swz() on byte position within the 16KB chunk
    const int pb  = e * 2;
    const int grp = pb >> 9;
    const int low = pb & 511;
    const int b4 = (low >> 4) & 1, b5 = (low >> 5) & 1, b6 = (low >> 6) & 1;
    const int b7 = (low >> 7) & 1, b8 = (low >> 8) & 1;
    const int a6 = b6 ^ b8, a5 = b5 ^ b7, a4 = b4 ^ a6;
    const int a = (grp << 9) | (low & 15) | (a4 << 4) | (a5 << 5) | (a6 << 6) | (b7 << 7) | (b8 << 8);
    const int lrow = a >> 6;            // 0..255
    const int kl   = (a & 63) >> 1;     // 0..31
    const int g = lrow >> 6, rowin = lrow & 63;
    const int j = g * 256 + strip * 64 + rowin;   // 0..1023
    const int k = ck * 32 + kl;
    if (isX) {
        float val;
        if (k < DIN)       val = (j < 768) ? Wioux[j * DIN + k] : Wfx[(j - 768) * DIN + k];
        else if (k == 319) val = (j < 768) ? (bioux[j] + biouh[j]) : (bfx[j - 768] + bfh[j - 768]);
        else               val = 0.0f;
        packWx[id] = f2bf(val);
    } else {
        const float val = (j < 768) ? Wiouh[j * MDIM + k] : Wfh[(j - 768) * MDIM + k];
        packWh[id] = f2bf(val);
    }
}

// ---------------------------------------------------------------------------
// Level kernel. Block = (node, strip): 128 batch rows x 64 m-cols (x4 gates).
// MODE 0: root child. MODE 1: child. MODE 2: proj (HF = h.Wh^T, tile layout).
// 512 threads / 8 waves (wr=wave>>2 row-half, wm=wave&3 m-substrip).
// Counted-vmcnt 2-phase pipeline: issue A-loads + W-glls for chunk t+1,
// vmcnt(4) (chunk t staged) -> barrier A -> ds_read+MFMA -> late A cvt+ds_write
// -> lgkmcnt(0) -> barrier B. No vmcnt(0) drain in the main loop.
// ---------------------------------------------------------------------------
template<int MODE>
__global__ __launch_bounds__(512, 4) void level_kernel(
    const float* __restrict__ Asrc,   // inputs (child) or h section (proj)
    const float* __restrict__ prob,
    const ushort* __restrict__ packW, // packWx (child) or packWh (proj)
    float* __restrict__ out,          // [c | h] sections
    ushort* __restrict__ HF,          // proj: write; child MODE1: read
    int level_start, int plevel_start)
{
    constexpr int NCK = (MODE == 2) ? NCK_H : NCK_X;
    constexpr int AST = (MODE == 2) ? MDIM : DIN;   // A row stride (floats)

    __shared__ __align__(16) ushort ldsA[2][BATCH * 32];   // 2 x 8 KB
    __shared__ __align__(16) ushort ldsW[2][256 * 32];     // 2 x 16 KB

    const int tid   = threadIdx.x;
    const int node  = level_start + (blockIdx.x >> 2);
    const int strip = blockIdx.x & 3;
    const int c0    = strip * 64;

    int parent = 0; float scale = 0.0f;
    if (MODE == 1) {
        parent = (node - 1) / 10;
        scale  = prob[(size_t)parent * NNODES + node];
    }

    const int wave = tid >> 6, lane = tid & 63;
    const int wr = wave >> 2, wm = wave & 3;
    const int l15 = lane & 15, kq = lane >> 4;

    f32x4 acc[4][4];
    const f32x4 zero4 = {0.f, 0.f, 0.f, 0.f};
#pragma unroll
    for (int t = 0; t < 4; ++t)
#pragma unroll
        for (int g = 0; g < 4; ++g) acc[t][g] = zero4;

    // A staging: thread -> (row srow, 16B segment)
    const int srow = tid >> 2;
    const int se8  = (tid & 3) * 8;                 // element offset 0/8/16/24
    const float* arow = Asrc + ((size_t)node * BATCH + srow) * AST;
    const int aOff = swz(srow * 64 + se8 * 2);

    // fragment LDS offsets (constant across chunks)
    int aoff[4], boff[4];
#pragma unroll
    for (int t = 0; t < 4; ++t) aoff[t] = swz((wr * 64 + t * 16 + l15) * 64 + kq * 16);
#pragma unroll
    for (int g = 0; g < 4; ++g) boff[g] = swz((g * 64 + wm * 16 + l15) * 64 + kq * 16);

    const ushort* wbase = packW + (size_t)(strip * NCK) * CHUNK_ELEMS;

    float4 va0, va1;
    auto issueA = [&](int ck) {
        const float* p = arow + ck * 32 + se8;
        va0 = *(const float4*)p;          // rows 16B-aligned
        va1 = *(const float4*)(p + 4);    // tail overread masked in writeA
    };
    auto writeA = [&](int ck, int buf) {
        float v[8] = {va0.x, va0.y, va0.z, va0.w, va1.x, va1.y, va1.z, va1.w};
        if (MODE != 2) {
            const int ge = ck * 32 + se8;
            if (ge + 7 >= DIN) {
#pragma unroll
                for (int j = 0; j < 8; ++j) {
                    const int gk = ge + j;
                    if (gk >= DIN) v[j] = (gk == 319) ? 1.0f : 0.0f;  // bias lane
                }
            }
        }
        union { __hip_bfloat162 h2[4]; int4 q; } pk;
#pragma unroll
        for (int j = 0; j < 4; ++j)
            pk.h2[j] = __float22bfloat162_rn(make_float2(v[2 * j], v[2 * j + 1]));
        *(int4*)((char*)ldsA[buf] + aOff) = pk.q;
    };
    auto issueW = [&](int ck, int buf) {
        const ushort* g0 = wbase + (size_t)ck * CHUNK_ELEMS + wave * 1024 + lane * 8;
        ushort* l0 = &ldsW[buf][wave * 1024];
        __builtin_amdgcn_global_load_lds(
            (const __attribute__((address_space(1))) unsigned*)(const void*)g0,
            (__attribute__((address_space(3))) unsigned*)(void*)l0, 16, 0, 0);
        __builtin_amdgcn_global_load_lds(
            (const __attribute__((address_space(1))) unsigned*)(const void*)(g0 + 512),
            (__attribute__((address_space(3))) unsigned*)(void*)(l0 + 512), 16, 0, 0);
    };
    auto compute = [&](int buf) {
        s16x8 af[4], bfr[4];
        char* pA = (char*)ldsA[buf];
        char* pW = (char*)ldsW[buf];
#pragma unroll
        for (int i = 0; i < 4; ++i) af[i] = *(const s16x8*)(pA + aoff[i]);
#pragma unroll
        for (int g = 0; g < 4; ++g) bfr[g] = *(const s16x8*)(pW + boff[g]);
#pragma unroll
        for (int i = 0; i < 4; ++i)
#pragma unroll
            for (int g = 0; g < 4; ++g)
                acc[i][g] = __builtin_amdgcn_mfma_f32_16x16x32_bf16(af[i], bfr[g], acc[i][g], 0, 0, 0);
    };

    // prologue: stage chunk 0 into buf 0 (A regs consumed immediately; W glls fly)
    issueA(0);
    issueW(0, 0);
    writeA(0, 0);   // compiler inserts vmcnt for va use (W glls stay outstanding)

    int b = 0;
    for (int t = 0; t < NCK - 1; ++t) {
        issueA(t + 1);            // 2 vm loads -> regs
        issueW(t + 1, b ^ 1);     // 2 glls -> other buffer
        asm volatile("s_waitcnt vmcnt(4) lgkmcnt(0)" ::: "memory");  // chunk t fully staged
        __builtin_amdgcn_sched_barrier(0);
        __builtin_amdgcn_s_barrier();
        __builtin_amdgcn_sched_barrier(0);
        compute(b);
        writeA(t + 1, b ^ 1);     // late: vmcnt(2) auto-inserted for va
        asm volatile("s_waitcnt lgkmcnt(0)" ::: "memory");
        __builtin_amdgcn_sched_barrier(0);
        __builtin_amdgcn_s_barrier();
        __builtin_amdgcn_sched_barrier(0);
        b ^= 1;
    }
    asm volatile("s_waitcnt vmcnt(0) lgkmcnt(0)" ::: "memory");      // last W glls
    __builtin_amdgcn_sched_barrier(0);
    __builtin_amdgcn_s_barrier();
    __builtin_amdgcn_sched_barrier(0);
    compute(b);

    // ---- epilogue ----
    const int m = c0 + wm * 16 + l15;   // feature col 0..255, fixed per lane

    if (MODE == 2) {
        // HF tile layout: [pidx][strip][t][g][tid][r], 8B coalesced stores
        ushort* hfw = HF + (size_t)(node - level_start) * HF_PER_P + strip * HF_PER_PS;
#pragma unroll
        for (int t = 0; t < 4; ++t)
#pragma unroll
            for (int g = 0; g < 4; ++g) {
                union { __hip_bfloat162 h2[2]; uint2 q; } pk;
                pk.h2[0] = __float22bfloat162_rn(make_float2(acc[t][g][0], acc[t][g][1]));
                pk.h2[1] = __float22bfloat162_rn(make_float2(acc[t][g][2], acc[t][g][3]));
                *(uint2*)(hfw + (t * 4 + g) * 2048 + tid * 4) = pk.q;
            }
        return;
    }

    const float* cprev = out + (size_t)parent * BATCH * MDIM;
    const ushort* hfb = (MODE == 1)
        ? (HF + (size_t)(parent - plevel_start) * HF_PER_P + strip * HF_PER_PS)
        : (const ushort*)0;
    float* cOut = out;
    float* hOut = out + NBM;

#pragma unroll
    for (int t = 0; t < 4; ++t) {
        const int b0 = wr * 64 + t * 16 + (kq << 2);
        u16x4 qi = {0,0,0,0}, qo = {0,0,0,0}, qu = {0,0,0,0}, qf = {0,0,0,0};
        if (MODE == 1) {
            qi = *(const u16x4*)(hfb + (t * 4 + 0) * 2048 + tid * 4);
            qo = *(const u16x4*)(hfb + (t * 4 + 1) * 2048 + tid * 4);
            qu = *(const u16x4*)(hfb + (t * 4 + 2) * 2048 + tid * 4);
            qf = *(const u16x4*)(hfb + (t * 4 + 3) * 2048 + tid * 4);
        }
#pragma unroll
        for (int r = 0; r < 4; ++r) {
            const int brow = b0 + r;
            float cn, hn;
            if (MODE == 1) {
                const float pc = scale * cprev[(size_t)brow * MDIM + m];
                const float iv = __builtin_fmaf(scale, bf2f(qi[r]), acc[t][0][r]);
                const float ov = __builtin_fmaf(scale, bf2f(qo[r]), acc[t][1][r]);
                const float uv = __builtin_fmaf(scale, bf2f(qu[r]), acc[t][2][r]);
                const float fv = __builtin_fmaf(scale, bf2f(qf[r]), acc[t][3][r]);
                cn = sig_(iv) * tanh_(uv) + sig_(fv) * pc;
                hn = sig_(ov) * tanh_(cn);
            } else {
                cn = sig_(acc[t][0][r]) * tanh_(acc[t][2][r]);
                hn = sig_(acc[t][1][r]) * tanh_(cn);
            }
            const size_t o = ((size_t)node * BATCH + brow) * MDIM + m;
            cOut[o] = cn;
            hOut[o] = hn;
        }
    }
}

// ---------------------------------------------------------------------------
extern "C" void kernel_launch(void* const* d_in, const int* in_sizes, int n_in,
                              void* d_out, int out_size, void* d_ws, size_t ws_size,
                              hipStream_t stream) {
    const float* inputs = (const float*)d_in[0];
    const float* prob   = (const float*)d_in[1];
    const float* Wioux  = (const float*)d_in[2];
    const float* bioux  = (const float*)d_in[3];
    const float* Wiouh  = (const float*)d_in[4];
    const float* biouh  = (const float*)d_in[5];
    const float* Wfx    = (const float*)d_in[6];
    const float* bfx    = (const float*)d_in[7];
    const float* Wfh    = (const float*)d_in[8];
    const float* bfh    = (const float*)d_in[9];
    float* out = (float*)d_out;

    // ws: packWx | packWh | HF  (~27.4 MB)
    ushort* packWx = (ushort*)d_ws;
    ushort* packWh = packWx + XW_ELEMS;
    ushort* HF     = packWh + HW_ELEMS;

    const int prepTotal = XW_ELEMS + HW_ELEMS;
    prep_kernel<<<(prepTotal + 255) / 256, 256, 0, stream>>>(
        Wioux, bioux, Wiouh, biouh, Wfx, bfx, Wfh, bfh, packWx, packWh);

    const float* hsec = out + NBM;

    // level 0 (root)
    level_kernel<0><<<dim3(4),    512, 0, stream>>>(inputs, prob, packWx, out, HF, 0, 0);
    level_kernel<2><<<dim3(4),    512, 0, stream>>>(hsec,   prob, packWh, out, HF, 0, 0);
    // level 1
    level_kernel<1><<<dim3(40),   512, 0, stream>>>(inputs, prob, packWx, out, HF, 1, 0);
    level_kernel<2><<<dim3(40),   512, 0, stream>>>(hsec,   prob, packWh, out, HF, 1, 1);
    // level 2
    level_kernel<1><<<dim3(400),  512, 0, stream>>>(inputs, prob, packWx, out, HF, 11, 1);
    level_kernel<2><<<dim3(400),  512, 0, stream>>>(hsec,   prob, packWh, out, HF, 11, 11);
    // level 3
    level_kernel<1><<<dim3(4000), 512, 0, stream>>>(inputs, prob, packWx, out, HF, 111, 11);
}